// Round 4
// baseline (2246.049 us; speedup 1.0000x reference)
//
#include <hip/hip_runtime.h>
#include <math.h>

#define N_EDGESC  1048576
#define N_GRAPHSC 8192
#define NPG 32     // nodes per graph
#define EPG 128    // edges per graph
#define FXD 78
#define F2C 156
#define F3C 312
#define GHC 156    // Wg1 out
#define GOC 128    // Wg2 out
#define HS  36     // padded node-stride
#define RBK 16     // rows per block in MLP kernels

// ---------------------------------------------------------------------------
// IN-PLACE multi-row A-aggregation: H[k][r] <- sum_c H[k][c] * A[r][c].
template<int FIN, int ROWS>
__device__ __forceinline__ void a_mult_ip(float* __restrict__ H,
                                          const float* __restrict__ As, int t) {
  const int r0 = (t & 7) * 4;
  const int g = t >> 3;
  float acc[ROWS][4];
  float* rowp[ROWS];
  bool valid[ROWS];
#pragma unroll
  for (int j = 0; j < ROWS; ++j) {
    int k = g + 32 * j;
    valid[j] = (k < FIN);
    rowp[j] = H + k * HS;
    acc[j][0] = acc[j][1] = acc[j][2] = acc[j][3] = 0.f;
  }
#pragma unroll
  for (int c = 0; c < NPG; c += 4) {
    float4 a0 = *(const float4*)(As + (c + 0) * HS + r0);
    float4 a1 = *(const float4*)(As + (c + 1) * HS + r0);
    float4 a2 = *(const float4*)(As + (c + 2) * HS + r0);
    float4 a3 = *(const float4*)(As + (c + 3) * HS + r0);
#pragma unroll
    for (int j = 0; j < ROWS; ++j) {
      if (valid[j]) {
        float4 h4 = *(const float4*)(rowp[j] + c);
        acc[j][0] = fmaf(h4.x, a0.x, acc[j][0]); acc[j][1] = fmaf(h4.x, a0.y, acc[j][1]);
        acc[j][2] = fmaf(h4.x, a0.z, acc[j][2]); acc[j][3] = fmaf(h4.x, a0.w, acc[j][3]);
        acc[j][0] = fmaf(h4.y, a1.x, acc[j][0]); acc[j][1] = fmaf(h4.y, a1.y, acc[j][1]);
        acc[j][2] = fmaf(h4.y, a1.z, acc[j][2]); acc[j][3] = fmaf(h4.y, a1.w, acc[j][3]);
        acc[j][0] = fmaf(h4.z, a2.x, acc[j][0]); acc[j][1] = fmaf(h4.z, a2.y, acc[j][1]);
        acc[j][2] = fmaf(h4.z, a2.z, acc[j][2]); acc[j][3] = fmaf(h4.z, a2.w, acc[j][3]);
        acc[j][0] = fmaf(h4.w, a3.x, acc[j][0]); acc[j][1] = fmaf(h4.w, a3.y, acc[j][1]);
        acc[j][2] = fmaf(h4.w, a3.z, acc[j][2]); acc[j][3] = fmaf(h4.w, a3.w, acc[j][3]);
      }
    }
  }
#pragma unroll
  for (int j = 0; j < ROWS; ++j) {
    if (valid[j]) {
      float4 o = {acc[j][0], acc[j][1], acc[j][2], acc[j][3]};
      *(float4*)(rowp[j] + r0) = o;
    }
  }
}

// ---------------------------------------------------------------------------
// Balanced mm: group g owns features f = 2g + 64p (p<P), packed contiguously
// in Wp as GW floats per group per k-row (row stride 32*GW). Every wave
// issues the same FMA count -> no worst-SIMD hotspot. 1 LDS b128 per k.
template<int FIN, int FOUT, int GW, int P, bool RELU, bool POOL>
__device__ __forceinline__ void mm_packed(const float* __restrict__ AH,
                                          const float* __restrict__ Wp,
                                          const float* __restrict__ bias,
                                          float* __restrict__ Hout,
                                          unsigned* __restrict__ gmax, int t) {
  const int n0 = (t & 7) * 4;
  const int g = t >> 3;
  const float* wrow = Wp + g * GW;
  float acc[P][2][4];
#pragma unroll
  for (int p = 0; p < P; ++p)
#pragma unroll
    for (int j = 0; j < 2; ++j)
#pragma unroll
      for (int i = 0; i < 4; ++i) acc[p][j][i] = 0.f;

#pragma unroll 2
  for (int k = 0; k < FIN; ++k) {
    float4 h = *(const float4*)(AH + k * HS + n0);
    const float* wp = wrow + (size_t)k * (32 * GW);
    float wv[2 * P];
    if constexpr (P == 2) {            // GW=4, 4-aligned
      float4 w = *(const float4*)wp;
      wv[0] = w.x; wv[1] = w.y; wv[2] = w.z; wv[3] = w.w;
    } else if constexpr (P == 3) {     // GW=6, 2-aligned
      float2 a = *(const float2*)wp;
      float2 b = *(const float2*)(wp + 2);
      float2 c = *(const float2*)(wp + 4);
      wv[0] = a.x; wv[1] = a.y; wv[2] = b.x; wv[3] = b.y; wv[4] = c.x; wv[5] = c.y;
    } else {                           // P==5, GW=12, 4-aligned
      float4 a = *(const float4*)wp;
      float4 b = *(const float4*)(wp + 4);
      float2 c = *(const float2*)(wp + 8);
      wv[0] = a.x; wv[1] = a.y; wv[2] = a.z; wv[3] = a.w;
      wv[4] = b.x; wv[5] = b.y; wv[6] = b.z; wv[7] = b.w;
      wv[8] = c.x; wv[9] = c.y;
    }
#pragma unroll
    for (int p = 0; p < P; ++p)
#pragma unroll
      for (int j = 0; j < 2; ++j) {
        float w = wv[2 * p + j];
        acc[p][j][0] = fmaf(h.x, w, acc[p][j][0]);
        acc[p][j][1] = fmaf(h.y, w, acc[p][j][1]);
        acc[p][j][2] = fmaf(h.z, w, acc[p][j][2]);
        acc[p][j][3] = fmaf(h.w, w, acc[p][j][3]);
      }
  }
#pragma unroll
  for (int p = 0; p < P; ++p) {
    const int f0 = 2 * g + 64 * p;
    if (f0 < FOUT) {
#pragma unroll
      for (int j = 0; j < 2; ++j) {
        const int f = f0 + j;
        float bb = bias[f];
        float o0 = acc[p][j][0] + bb, o1 = acc[p][j][1] + bb;
        float o2 = acc[p][j][2] + bb, o3 = acc[p][j][3] + bb;
        if (RELU) {
          o0 = fmaxf(o0, 0.f); o1 = fmaxf(o1, 0.f);
          o2 = fmaxf(o2, 0.f); o3 = fmaxf(o3, 0.f);
        }
        if constexpr (POOL) {
          float m = fmaxf(fmaxf(o0, o1), fmaxf(o2, o3));
          atomicMax(&gmax[f], __float_as_uint(m));  // relu'd >= 0 -> monotone
        } else {
          float4 o = {o0, o1, o2, o3};
          *(float4*)(Hout + f * HS + n0) = o;
        }
      }
    }
  }
}

// ---------------------------------------------------------------------------
// Weight pre-pack: dst[k][g*GW + 2p+j] = (2g+64p < FOUT) ? src[k][2g+64p+j] : 0
__global__ __launch_bounds__(256)
void pack_w(const float* __restrict__ src, float* __restrict__ dst,
            int FIN, int FOUT, int GW, int P) {
  int idx = blockIdx.x * 256 + threadIdx.x;
  int total = FIN * 32 * GW;
  if (idx >= total) return;
  int rowsz = 32 * GW;
  int row = idx / rowsz;
  int r = idx - row * rowsz;
  int g = r / GW;
  int u = r - g * GW;
  int p = u >> 1;
  int f0 = 2 * g + 64 * p;
  float v = 0.f;
  if (u < 2 * P && f0 < FOUT) v = src[(size_t)row * FOUT + f0 + (u & 1)];
  dst[idx] = v;
}

// ---------------------------------------------------------------------------
// One block per graph, blockIdx.y = drug. LDS 38400 B -> 4 blocks/CU.
__global__ __launch_bounds__(256, 4)
void drug_kernel(const float* __restrict__ x1, const int* __restrict__ ei1,
                 const float* __restrict__ x2, const int* __restrict__ ei2,
                 const float* __restrict__ W1p, const float* __restrict__ b1,
                 const float* __restrict__ W2p, const float* __restrict__ b2,
                 const float* __restrict__ W3p, const float* __restrict__ b3,
                 const float* __restrict__ Wg1, const float* __restrict__ bg1,
                 const float* __restrict__ Wg2, const float* __restrict__ bg2,
                 float* __restrict__ gout) {
  __shared__ __align__(16) float X[F2C * HS];   // 22464 B
  __shared__ __align__(16) float Y[FXD * HS];   // 11232 B
  __shared__ __align__(16) float As[NPG * HS];  //  4608 B
  // aliases into Y (lifetimes disjoint):
  float* deg = Y;
  float* gbuf = Y;
  unsigned* gbufU = (unsigned*)Y;
  float* gg = Y + 512;

  const int t = threadIdx.x;
  const int gid = blockIdx.x;
  const int drug = blockIdx.y;
  const float* __restrict__ x = drug ? x2 : x1;
  const int* __restrict__ ei = drug ? ei2 : ei1;
  const int nbase = gid * NPG;

  // ---- P0: zero deg + As, load x^T -> X
  if (t < NPG) deg[t] = 0.f;
  for (int i = t; i < NPG * HS; i += 256) As[i] = 0.f;
  const float* xg = x + (size_t)gid * (NPG * FXD);
  for (int i = t; i < (NPG * FXD) / 4; i += 256) {
    float4 v = ((const float4*)xg)[i];
    const float* vp = (const float*)&v;
    int idx = i * 4;
#pragma unroll
    for (int j = 0; j < 4; ++j) {
      int id2 = idx + j;
      int n = id2 / FXD;
      int k = id2 - n * FXD;
      X[k * HS + n] = vp[j];
    }
  }
  int s = 0, d = 0;
  if (t < EPG) {
    s = ei[(size_t)gid * EPG + t] - nbase;
    d = ei[(size_t)N_EDGESC + (size_t)gid * EPG + t] - nbase;
  }
  __syncthreads();
  if (t < EPG) atomicAdd(&deg[s], 1.0f);
  __syncthreads();
  if (t < EPG) {
    float w = rsqrtf(deg[s] + 1.0f) * rsqrtf(deg[d] + 1.0f);
    atomicAdd(&As[d * HS + s], w);   // A[s][d]: msg d->s
  }
  if (t < NPG) atomicAdd(&As[t * HS + t], 1.0f / (deg[t] + 1.0f));
  __syncthreads();

  // ---- layer 1
  a_mult_ip<FXD, 3>(X, As, t);
  __syncthreads();
  mm_packed<FXD, FXD, 4, 2, true, false>(X, W1p, b1, Y, nullptr, t);  // deg dead
  __syncthreads();
  // ---- layer 2
  a_mult_ip<FXD, 3>(Y, As, t);
  __syncthreads();
  mm_packed<FXD, F2C, 6, 3, true, false>(Y, W2p, b2, X, nullptr, t);
  __syncthreads();
  // ---- layer 3 + pool (Y dead: gbuf lives there)
  a_mult_ip<F2C, 5>(X, As, t);
  for (int i = t; i < F3C; i += 256) gbufU[i] = 0u;
  __syncthreads();
  mm_packed<F2C, F3C, 12, 5, true, true>(X, W3p, b3, nullptr, gbufU, t);
  __syncthreads();

  // ---- graph MLP
  if (t < GHC) {
    float acc = 0.f;
#pragma unroll 2
    for (int k = 0; k < F3C; k += 4) {
      float4 gv = *(const float4*)(gbuf + k);
      acc = fmaf(gv.x, Wg1[(k + 0) * GHC + t], acc);
      acc = fmaf(gv.y, Wg1[(k + 1) * GHC + t], acc);
      acc = fmaf(gv.z, Wg1[(k + 2) * GHC + t], acc);
      acc = fmaf(gv.w, Wg1[(k + 3) * GHC + t], acc);
    }
    gg[t] = fmaxf(acc + bg1[t], 0.f);
  }
  __syncthreads();
  if (t < GOC) {
    float acc = 0.f;
#pragma unroll 2
    for (int k = 0; k < GHC; k += 4) {
      float4 gv = *(const float4*)(gg + k);
      acc = fmaf(gv.x, Wg2[(k + 0) * GOC + t], acc);
      acc = fmaf(gv.y, Wg2[(k + 1) * GOC + t], acc);
      acc = fmaf(gv.z, Wg2[(k + 2) * GOC + t], acc);
      acc = fmaf(gv.w, Wg2[(k + 3) * GOC + t], acc);
    }
    gout[((size_t)drug * N_GRAPHSC + gid) * GOC + t] = acc + bg2[t];
  }
}

// ---------------------------------------------------------------------------
// Cell MLP: 16 rows/block, microtile 4 rows x 8 feats (32 FMA per b128).
__global__ __launch_bounds__(256, 3)
void cell_kernel(const float* __restrict__ cell,
                 const float* __restrict__ Wr1, const float* __restrict__ br1,
                 const float* __restrict__ Wr2, const float* __restrict__ br2,
                 const float* __restrict__ Wr3, const float* __restrict__ br3,
                 float* __restrict__ cout) {
  __shared__ __align__(16) float U[512 * RBK];   // 32768 B
  __shared__ __align__(16) float h2[256 * RBK];  // 16384 B
  const int t = threadIdx.x;
  const int R = blockIdx.x * RBK;
  const int r0 = (t & 3) * 4;
  const int f = t >> 2;  // [0,64)

  float acc[4][8];
#pragma unroll
  for (int i = 0; i < 4; ++i)
#pragma unroll
    for (int j = 0; j < 8; ++j) acc[i][j] = 0.f;

  for (int k0 = 0; k0 < 1000; k0 += 200) {
    __syncthreads();
    for (int i = t; i < 800; i += 256) {       // 16 rows x 50 float4
      int r = i / 50, k4 = i - r * 50;
      float4 v = *(const float4*)(cell + (size_t)(R + r) * 1000 + k0 + k4 * 4);
      int kk = k4 * 4;
      U[(kk + 0) * RBK + r] = v.x; U[(kk + 1) * RBK + r] = v.y;
      U[(kk + 2) * RBK + r] = v.z; U[(kk + 3) * RBK + r] = v.w;
    }
    __syncthreads();
#pragma unroll 4
    for (int k = 0; k < 200; ++k) {
      float4 h = *(const float4*)(U + k * RBK + r0);
      const float* wr = Wr1 + (size_t)(k0 + k) * 512 + f;
#pragma unroll
      for (int j = 0; j < 8; ++j) {
        float w = wr[j * 64];
        acc[0][j] = fmaf(h.x, w, acc[0][j]);
        acc[1][j] = fmaf(h.y, w, acc[1][j]);
        acc[2][j] = fmaf(h.z, w, acc[2][j]);
        acc[3][j] = fmaf(h.w, w, acc[3][j]);
      }
    }
  }
  __syncthreads();   // ct region dead -> U becomes h1
#pragma unroll
  for (int j = 0; j < 8; ++j) {
    int ff = f + j * 64;
    float bb = br1[ff];
    float4 o;
    o.x = fmaxf(acc[0][j] + bb, 0.f); o.y = fmaxf(acc[1][j] + bb, 0.f);
    o.z = fmaxf(acc[2][j] + bb, 0.f); o.w = fmaxf(acc[3][j] + bb, 0.f);
    *(float4*)(U + ff * RBK + r0) = o;
  }
  __syncthreads();

  float a2[4][4];
#pragma unroll
  for (int i = 0; i < 4; ++i)
#pragma unroll
    for (int j = 0; j < 4; ++j) a2[i][j] = 0.f;
#pragma unroll 4
  for (int k = 0; k < 512; ++k) {
    float4 h = *(const float4*)(U + k * RBK + r0);
    const float* wr = Wr2 + (size_t)k * 256 + f;
#pragma unroll
    for (int j = 0; j < 4; ++j) {
      float w = wr[j * 64];
      a2[0][j] = fmaf(h.x, w, a2[0][j]);
      a2[1][j] = fmaf(h.y, w, a2[1][j]);
      a2[2][j] = fmaf(h.z, w, a2[2][j]);
      a2[3][j] = fmaf(h.w, w, a2[3][j]);
    }
  }
#pragma unroll
  for (int j = 0; j < 4; ++j) {   // h2 disjoint from U: no barrier needed
    int ff = f + j * 64;
    float bb = br2[ff];
    float4 o;
    o.x = fmaxf(a2[0][j] + bb, 0.f); o.y = fmaxf(a2[1][j] + bb, 0.f);
    o.z = fmaxf(a2[2][j] + bb, 0.f); o.w = fmaxf(a2[3][j] + bb, 0.f);
    *(float4*)(h2 + ff * RBK + r0) = o;
  }
  __syncthreads();

  float a3[4][2];
#pragma unroll
  for (int i = 0; i < 4; ++i) { a3[i][0] = 0.f; a3[i][1] = 0.f; }
#pragma unroll 4
  for (int k = 0; k < 256; ++k) {
    float4 h = *(const float4*)(h2 + k * RBK + r0);
    const float* wr = Wr3 + (size_t)k * 128 + f;
#pragma unroll
    for (int j = 0; j < 2; ++j) {
      float w = wr[j * 64];
      a3[0][j] = fmaf(h.x, w, a3[0][j]);
      a3[1][j] = fmaf(h.y, w, a3[1][j]);
      a3[2][j] = fmaf(h.z, w, a3[2][j]);
      a3[3][j] = fmaf(h.w, w, a3[3][j]);
    }
  }
#pragma unroll
  for (int j = 0; j < 2; ++j) {
    int ff = f + j * 64;
    float bb = br3[ff];
#pragma unroll
    for (int i = 0; i < 4; ++i)
      cout[(size_t)(R + r0 + i) * GOC + ff] = a3[i][j] + bb;  // no relu
  }
}

// ---------------------------------------------------------------------------
// Head: 16 rows/block. U holds xct then h1; h2 separate. ~41.2 KB.
__global__ __launch_bounds__(256, 3)
void head_kernel(const float* __restrict__ g1, const float* __restrict__ g2,
                 const float* __restrict__ cc,
                 const float* __restrict__ Wf1, const float* __restrict__ bf1,
                 const float* __restrict__ Wf2, const float* __restrict__ bf2,
                 const float* __restrict__ Wo, const float* __restrict__ bo,
                 const float* __restrict__ pa, float* __restrict__ out) {
  __shared__ __align__(16) float U[512 * RBK];   // 32768 B
  __shared__ __align__(16) float h2[128 * RBK];  //  8192 B
  __shared__ float ssq[RBK];
  __shared__ float scal[RBK];
  __shared__ float red[256];

  const int t = threadIdx.x;
  const int R = blockIdx.x * RBK;
  if (t < RBK) ssq[t] = 0.f;
  __syncthreads();
  for (int i = t; i < 1536; i += 256) {   // 16 rows x 96 float4
    int r = i / 96, q = i - r * 96;
    int col = q * 4;
    const float* src;
    int c2;
    if (col < 128)      { src = g1; c2 = col; }
    else if (col < 256) { src = g2; c2 = col - 128; }
    else                { src = cc; c2 = col - 256; }
    float4 v = *(const float4*)(src + (size_t)(R + r) * GOC + c2);
    U[(col + 0) * RBK + r] = v.x; U[(col + 1) * RBK + r] = v.y;
    U[(col + 2) * RBK + r] = v.z; U[(col + 3) * RBK + r] = v.w;
    atomicAdd(&ssq[r], v.x * v.x + v.y * v.y + v.z * v.z + v.w * v.w);
  }
  __syncthreads();
  if (t < RBK) scal[t] = 1.0f / fmaxf(sqrtf(ssq[t]), 1e-12f);
  __syncthreads();

  const float a = pa[0];
  const int r0 = (t & 3) * 4;
  const int f = t >> 2;  // [0,64)

  float acc[4][8];
#pragma unroll
  for (int i = 0; i < 4; ++i)
#pragma unroll
    for (int j = 0; j < 8; ++j) acc[i][j] = 0.f;
#pragma unroll 4
  for (int k = 0; k < 384; ++k) {
    float4 h = *(const float4*)(U + k * RBK + r0);
    const float* wr = Wf1 + (size_t)k * 512 + f;
#pragma unroll
    for (int j = 0; j < 8; ++j) {
      float w = wr[j * 64];
      acc[0][j] = fmaf(h.x, w, acc[0][j]);
      acc[1][j] = fmaf(h.y, w, acc[1][j]);
      acc[2][j] = fmaf(h.z, w, acc[2][j]);
      acc[3][j] = fmaf(h.w, w, acc[3][j]);
    }
  }
  __syncthreads();   // xct dead -> U becomes h1
#pragma unroll
  for (int j = 0; j < 8; ++j) {
    int ff = f + j * 64;
    float bb = bf1[ff];
    float4 o;
    float v0 = acc[0][j] * scal[r0 + 0] + bb; o.x = v0 >= 0.f ? v0 : a * v0;
    float v1 = acc[1][j] * scal[r0 + 1] + bb; o.y = v1 >= 0.f ? v1 : a * v1;
    float v2 = acc[2][j] * scal[r0 + 2] + bb; o.z = v2 >= 0.f ? v2 : a * v2;
    float v3 = acc[3][j] * scal[r0 + 3] + bb; o.w = v3 >= 0.f ? v3 : a * v3;
    *(float4*)(U + ff * RBK + r0) = o;
  }
  __syncthreads();

  float a2[4][2];
#pragma unroll
  for (int i = 0; i < 4; ++i) { a2[i][0] = 0.f; a2[i][1] = 0.f; }
#pragma unroll 4
  for (int k = 0; k < 512; ++k) {
    float4 h = *(const float4*)(U + k * RBK + r0);
    const float* wr = Wf2 + (size_t)k * 128 + f;
#pragma unroll
    for (int j = 0; j < 2; ++j) {
      float w = wr[j * 64];
      a2[0][j] = fmaf(h.x, w, a2[0][j]);
      a2[1][j] = fmaf(h.y, w, a2[1][j]);
      a2[2][j] = fmaf(h.z, w, a2[2][j]);
      a2[3][j] = fmaf(h.w, w, a2[3][j]);
    }
  }
  {
#pragma unroll
    for (int j = 0; j < 2; ++j) {   // h2 disjoint from U
      int ff = f + j * 64;
      float bb = bf2[ff];
#pragma unroll
      for (int i = 0; i < 4; ++i) {
        float v = a2[i][j] + bb;
        v = v >= 0.f ? v : a * v;
        h2[ff * RBK + (r0 + i)] = v;
      }
    }
  }
  __syncthreads();

  {
    int rr = t >> 4, kp = t & 15;
    float p = 0.f;
#pragma unroll
    for (int jj = 0; jj < 8; ++jj) {
      int k = kp + 16 * jj;
      p = fmaf(h2[k * RBK + rr], Wo[k], p);
    }
    red[t] = p;
  }
  __syncthreads();
  if (t < RBK) {
    float ssum = bo[0];
#pragma unroll
    for (int i = 0; i < 16; ++i) ssum += red[t * 16 + i];
    out[R + t] = 1.0f / (1.0f + expf(-ssum));
  }
}

// ---------------------------------------------------------------------------
extern "C" void kernel_launch(void* const* d_in, const int* in_sizes, int n_in,
                              void* d_out, int out_size, void* d_ws, size_t ws_size,
                              hipStream_t stream) {
  const float* x1  = (const float*)d_in[0];
  const int*   ei1 = (const int*)d_in[1];
  const float* x2  = (const float*)d_in[2];
  const int*   ei2 = (const int*)d_in[3];
  const float* cel = (const float*)d_in[4];
  const float* W1  = (const float*)d_in[7];
  const float* b1  = (const float*)d_in[8];
  const float* W2  = (const float*)d_in[9];
  const float* b2  = (const float*)d_in[10];
  const float* W3  = (const float*)d_in[11];
  const float* b3  = (const float*)d_in[12];
  const float* Wg1 = (const float*)d_in[13];
  const float* bg1 = (const float*)d_in[14];
  const float* Wg2 = (const float*)d_in[15];
  const float* bg2 = (const float*)d_in[16];
  const float* Wr1 = (const float*)d_in[17];
  const float* br1 = (const float*)d_in[18];
  const float* Wr2 = (const float*)d_in[19];
  const float* br2 = (const float*)d_in[20];
  const float* Wr3 = (const float*)d_in[21];
  const float* br3 = (const float*)d_in[22];
  const float* Wf1 = (const float*)d_in[23];
  const float* bf1 = (const float*)d_in[24];
  const float* Wf2 = (const float*)d_in[25];
  const float* bf2 = (const float*)d_in[26];
  const float* Wo  = (const float*)d_in[27];
  const float* bo  = (const float*)d_in[28];
  const float* pa  = (const float*)d_in[29];

  float* ws    = (float*)d_ws;
  float* g1buf = ws;
  float* g2buf = ws + (size_t)N_GRAPHSC * GOC;
  float* cbuf  = ws + (size_t)2 * N_GRAPHSC * GOC;
  float* wpck  = ws + (size_t)3 * N_GRAPHSC * GOC;
  float* w1p   = wpck;                 // 78*128  =  9984
  float* w2p   = wpck + 9984;          // 78*192  = 14976
  float* w3p   = wpck + 9984 + 14976;  // 156*384 = 59904
  float* outp  = (float*)d_out;

  pack_w<<<dim3((78 * 128 + 255) / 256), dim3(256), 0, stream>>>(W1, w1p, FXD, FXD, 4, 2);
  pack_w<<<dim3((78 * 192 + 255) / 256), dim3(256), 0, stream>>>(W2, w2p, FXD, F2C, 6, 3);
  pack_w<<<dim3((156 * 384 + 255) / 256), dim3(256), 0, stream>>>(W3, w3p, F2C, F3C, 12, 5);

  dim3 dgrid(N_GRAPHSC, 2);
  drug_kernel<<<dgrid, dim3(256), 0, stream>>>(
      x1, ei1, x2, ei2, w1p, b1, w2p, b2, w3p, b3, Wg1, bg1, Wg2, bg2, g1buf);
  cell_kernel<<<dim3(N_GRAPHSC / RBK), dim3(256), 0, stream>>>(
      cel, Wr1, br1, Wr2, br2, Wr3, br3, cbuf);
  head_kernel<<<dim3(N_GRAPHSC / RBK), dim3(256), 0, stream>>>(
      g1buf, g2buf, cbuf, Wf1, bf1, Wf2, bf2, Wo, bo, pa, outp);
}